// Round 8
// baseline (531.662 us; speedup 1.0000x reference)
//
#include <hip/hip_runtime.h>
#include <cstdint>
#include <cstddef>
#include <utility>

#define Ndim 8
#define Odim 32
#define Cdim 16
#define Hdim 512
#define Rdim 8
#define TW 64
#define TH 4
#define NBW (Hdim/TW)     // 8   w-blocks
#define NBH (Hdim/TH)     // 128 h-blocks
#define OSPLIT 2
#define OPB (Odim/OSPLIT) // 16 o's per block

typedef _Float16 half2_t __attribute__((ext_vector_type(2)));

union U16 { uint4 u; half2_t h[4]; };

// compile-time unroll with literal indices
template <class F, int... Is>
__device__ __forceinline__ void unroll_impl(F&& f, std::integer_sequence<int, Is...>) {
    (f(std::integral_constant<int, Is>{}), ...);
}
template <int N, class F>
__device__ __forceinline__ void unrollN(F&& f) {
    unroll_impl(static_cast<F&&>(f), std::make_integer_sequence<int, N>{});
}

__device__ __forceinline__ half2_t pk(float a, float b) {
    half2_t h; h[0] = (_Float16)a; h[1] = (_Float16)b; return h;
}

#if defined(__has_builtin)
#if __has_builtin(__builtin_amdgcn_fdot2)
#define HAVE_FDOT2 1
#endif
#endif

__device__ __forceinline__ float fdot2f(half2_t a, half2_t b, float acc) {
#ifdef HAVE_FDOT2
    return __builtin_amdgcn_fdot2(a, b, acc, false);
#else
    return acc + (float)a[0] * (float)b[0] + (float)a[1] * (float)b[1];
#endif
}

// async global(16B/lane) -> LDS
__device__ __forceinline__ void stage16(const uint4* g, uint4* l) {
    __builtin_amdgcn_global_load_lds(
        (const __attribute__((address_space(1))) uint32_t*)g,
        (__attribute__((address_space(3))) uint32_t*)l, 16, 0, 0);
}

// DPP ladder full-wave64 sum; valid in lane 63.
template<int CTRL>
__device__ __forceinline__ float dppadd(float v) {
    return v + __int_as_float(__builtin_amdgcn_update_dpp(
        0, __float_as_int(v), CTRL, 0xf, 0xf, true));
}
__device__ __forceinline__ float wave_sum63(float v) {
    v = dppadd<0xB1>(v);
    v = dppadd<0x4E>(v);
    v = dppadd<0x141>(v);
    v = dppadd<0x140>(v);
    v = dppadd<0x142>(v);
    v = dppadd<0x143>(v);
    return v;
}

// Pre-pack L to f16.
//   lsigT[(o*H + h)*C + c] = (L*coupling)[o,c,h,:]  (A-side; uniform s_load)
//   lraw [(o*C + c)*H + w] = L[o,c,w,:]             (B-side; staging source)
__global__ __launch_bounds__(256)
void sylo_prep(const float* __restrict__ L, const float* __restrict__ coup,
               uint4* __restrict__ lsigT, uint4* __restrict__ lraw)
{
    int row = blockIdx.x * 256 + threadIdx.x;      // (o*C + c)*H + h
    int oc = row >> 9, h = row & 511;
    int o = oc >> 4, c = oc & 15;
    const float4* lp = (const float4*)(L + (size_t)row * Rdim);
    const float4* cp = (const float4*)(coup + (size_t)oc * Rdim);
    float4 l0 = lp[0], l1 = lp[1];
    float4 c0 = cp[0], c1 = cp[1];
    U16 s, r;
    s.h[0] = pk(l0.x * c0.x, l0.y * c0.y); s.h[1] = pk(l0.z * c0.z, l0.w * c0.w);
    s.h[2] = pk(l1.x * c1.x, l1.y * c1.y); s.h[3] = pk(l1.z * c1.z, l1.w * c1.w);
    r.h[0] = pk(l0.x, l0.y); r.h[1] = pk(l0.z, l0.w);
    r.h[2] = pk(l1.x, l1.y); r.h[3] = pk(l1.z, l1.w);
    lsigT[((size_t)o * Hdim + h) * Cdim + c] = s.u;
    lraw[row] = r.u;
}

// ---- shared per-o compute: fused T+P (no t2 buffer; A from SMEM, B from LDS) ----
template<int MODE>
__device__ __forceinline__ void compute_p(
    int o, int ruh, int j, const uint4 (&lwb)[Cdim][TW],
    const uint4* __restrict__ lsigT, const float* __restrict__ Lg,
    const float* __restrict__ coupg, const half2_t (&xa)[64], float (&p)[Ndim])
{
    unrollN<8>([&](auto ni) { p[decltype(ni)::value] = 0.f; });
    unrollN<8>([&](auto cpi) {
        constexpr int cp = decltype(cpi)::value;
        float tv[2];
        unrollN<2>([&](auto hi) {
            constexpr int half = decltype(hi)::value;
            constexpr int c = 2 * cp + half;
            U16 A, B;
            if (MODE < 2) {
                A.u = lsigT[((size_t)o * Hdim + ruh) * Cdim + c];
            } else {
                const float4* a0 = (const float4*)(Lg + ((size_t)(o * Cdim + c) * Hdim + ruh) * Rdim);
                const float4* cpp = (const float4*)(coupg + (size_t)(o * Cdim + c) * Rdim);
                float4 l0 = a0[0], l1 = a0[1];
                float4 c0 = cpp[0], c1 = cpp[1];
                A.h[0] = pk(l0.x * c0.x, l0.y * c0.y); A.h[1] = pk(l0.z * c0.z, l0.w * c0.w);
                A.h[2] = pk(l1.x * c1.x, l1.y * c1.y); A.h[3] = pk(l1.z * c1.z, l1.w * c1.w);
            }
            B.u = lwb[c][j];
            float t = 0.f;
            unrollN<4>([&](auto ri) {
                constexpr int r = decltype(ri)::value;
                t = fdot2f(A.h[r], B.h[r], t);
            });
            tv[half] = t;
        });
        half2_t t2 = pk(tv[0], tv[1]);
        unrollN<8>([&](auto ni) {
            constexpr int n = decltype(ni)::value;
            p[n] = fdot2f(t2, xa[cp * 8 + n], p[n]);
        });
    });
}

#define X_PROLOGUE                                                              \
    half2_t xa[64];                                                             \
    {                                                                           \
        const size_t HH = (size_t)Hdim * Hdim;                                  \
        const size_t q = (size_t)hh * Hdim + ww;                                \
        unrollN<8>([&](auto cpi) {                                              \
            unrollN<8>([&](auto ni) {                                           \
                constexpr int cp = decltype(cpi)::value, n = decltype(ni)::value;\
                xa[cp * 8 + n] = pk(Xg[(size_t)(n * Cdim + 2 * cp) * HH + q],   \
                                    Xg[(size_t)(n * Cdim + 2 * cp + 1) * HH + q]);\
            });                                                                 \
        });                                                                     \
    }

// PASS 0: P -> row sums (DPP, lane63 store) + col partials (exclusive LDS slots,
//         flushed every o).  LDS = 32K dbuf + 8K csl = 40K -> 4 blocks/CU.
template<int MODE>
__global__ __launch_bounds__(256, 4)
void sylo_p0(const float* __restrict__ Xg, const float* __restrict__ Lg,
             const float* __restrict__ coupg,
             const uint4* __restrict__ lsigT, const uint4* __restrict__ lraw,
             float* __restrict__ rsp, float* __restrict__ csp,
             float* __restrict__ rs, float* __restrict__ cs)
{
    const int tid = threadIdx.x;
    const int j = tid & 63, iw = tid >> 6;
    const int bw = blockIdx.x, bh = blockIdx.y, ob = blockIdx.z * OPB;
    const int w0 = bw * TW, h0 = bh * TH;
    const int hh = h0 + iw, ww = w0 + j;
    const size_t S = (size_t)Ndim * Odim * Hdim;

    __shared__ __align__(16) uint4 lw[2][Cdim][TW];   // 32 KB
    __shared__ float csl[TH][Ndim][TW];               // 8 KB

    X_PROLOGUE
    const int ruh = __builtin_amdgcn_readfirstlane(hh);

    if (MODE < 2) {
        unrollN<4>([&](auto ki) {
            constexpr int k = decltype(ki)::value;
            int c = iw * 4 + k;
            stage16(lraw + ((size_t)(ob * Cdim + c) * Hdim + w0 + j), &lw[0][c][0]);
        });
    }
    __syncthreads();

    for (int oo = 0; oo < OPB; ++oo) {
        const int o = ob + oo;
        const int cur = (MODE < 2) ? (oo & 1) : 0;

        if (MODE < 2) {
            if (oo + 1 < OPB) {
                unrollN<4>([&](auto ki) {
                    constexpr int k = decltype(ki)::value;
                    int c = iw * 4 + k;
                    stage16(lraw + ((size_t)((o + 1) * Cdim + c) * Hdim + w0 + j),
                            &lw[cur ^ 1][c][0]);
                });
            }
        } else {
            unrollN<4>([&](auto ki) {
                constexpr int k = decltype(ki)::value;
                int e = tid + k * 256, c = e >> 6, w = e & 63;
                const float4* gp = (const float4*)(Lg + ((size_t)(o * Cdim + c) * Hdim + w0 + w) * Rdim);
                float4 l0 = gp[0], l1 = gp[1];
                U16 t;
                t.h[0] = pk(l0.x, l0.y); t.h[1] = pk(l0.z, l0.w);
                t.h[2] = pk(l1.x, l1.y); t.h[3] = pk(l1.z, l1.w);
                lw[0][c][w] = t.u;
            });
            __syncthreads();
        }

        float p[Ndim];
        compute_p<MODE>(o, ruh, j, lw[cur], lsigT, Lg, coupg, xa, p);

        unrollN<8>([&](auto ni) {
            constexpr int n = decltype(ni)::value;
            float r = wave_sum63(p[n]);
            if (j == 63) {
                size_t i0 = (size_t)(n * Odim + o) * Hdim + hh;
                if (MODE == 0) rsp[(size_t)bw * S + i0] = r;
                else atomicAdd(&rs[i0], r);
            }
            csl[iw][n][j] = p[n];
        });
        __syncthreads();
        unrollN<2>([&](auto ki) {
            constexpr int k = decltype(ki)::value;
            int f = tid + k * 256;             // 0..511
            int n = f >> 6, jj = f & 63;
            float v = csl[0][n][jj] + csl[1][n][jj] + csl[2][n][jj] + csl[3][n][jj];
            size_t idx = (size_t)(n * Odim + o) * Hdim + w0 + jj;
            if (MODE == 0) csp[(size_t)bh * S + idx] = v;
            else atomicAdd(&cs[idx], v);
        });
        __syncthreads();   // csl + dbuf reusable; drains this iter's stage DMA
    }
}

// PASS 1: recompute P, combine with rs/cs/bias, write out.  LDS = 32K -> 5 blocks/CU.
template<int MODE>
__global__ __launch_bounds__(256, 5)
void sylo_p1(const float* __restrict__ Xg, const float* __restrict__ Lg,
             const float* __restrict__ coupg, const float* __restrict__ biasg,
             const uint4* __restrict__ lsigT, const uint4* __restrict__ lraw,
             float* __restrict__ outg,
             const float* __restrict__ rs, const float* __restrict__ cs)
{
    const int tid = threadIdx.x;
    const int j = tid & 63, iw = tid >> 6;
    const int bw = blockIdx.x, bh = blockIdx.y, ob = blockIdx.z * OPB;
    const int w0 = bw * TW, h0 = bh * TH;
    const int hh = h0 + iw, ww = w0 + j;

    __shared__ __align__(16) uint4 lw[2][Cdim][TW];   // 32 KB only

    X_PROLOGUE
    const int ruh = __builtin_amdgcn_readfirstlane(hh);

    if (MODE < 2) {
        unrollN<4>([&](auto ki) {
            constexpr int k = decltype(ki)::value;
            int c = iw * 4 + k;
            stage16(lraw + ((size_t)(ob * Cdim + c) * Hdim + w0 + j), &lw[0][c][0]);
        });
    }
    __syncthreads();

    for (int oo = 0; oo < OPB; ++oo) {
        const int o = ob + oo;
        const int cur = (MODE < 2) ? (oo & 1) : 0;

        if (MODE < 2) {
            if (oo + 1 < OPB) {
                unrollN<4>([&](auto ki) {
                    constexpr int k = decltype(ki)::value;
                    int c = iw * 4 + k;
                    stage16(lraw + ((size_t)((o + 1) * Cdim + c) * Hdim + w0 + j),
                            &lw[cur ^ 1][c][0]);
                });
            }
        } else {
            unrollN<4>([&](auto ki) {
                constexpr int k = decltype(ki)::value;
                int e = tid + k * 256, c = e >> 6, w = e & 63;
                const float4* gp = (const float4*)(Lg + ((size_t)(o * Cdim + c) * Hdim + w0 + w) * Rdim);
                float4 l0 = gp[0], l1 = gp[1];
                U16 t;
                t.h[0] = pk(l0.x, l0.y); t.h[1] = pk(l0.z, l0.w);
                t.h[2] = pk(l1.x, l1.y); t.h[3] = pk(l1.z, l1.w);
                lw[0][c][w] = t.u;
            });
            __syncthreads();
        }

        float p[Ndim];
        compute_p<MODE>(o, ruh, j, lw[cur], lsigT, Lg, coupg, xa, p);

        float bb = biasg[o];
        unrollN<8>([&](auto ni) {
            constexpr int n = decltype(ni)::value;
            size_t i0 = (size_t)(n * Odim + o) * Hdim;
            float rv = rs[i0 + (size_t)ruh];     // uniform -> s_load
            float cv = cs[i0 + ww];              // coalesced, L2-hot
            float v = rv + cv - p[n] + bb;
            if (hh == ww) v = 0.f;
            outg[(i0 + hh) * Hdim + ww] = v;
        });
        __syncthreads();   // dbuf reusable; drains this iter's stage DMA
    }
}

__global__ __launch_bounds__(256)
void sylo_reduce(const float* __restrict__ rsp, const float* __restrict__ csp,
                 float* __restrict__ rs, float* __restrict__ cs)
{
    int t = blockIdx.x * 256 + threadIdx.x;   // < 131072
    const size_t S = (size_t)Ndim * Odim * Hdim;
    float a = 0.f;
    #pragma unroll
    for (int k = 0; k < NBW; ++k) a += rsp[(size_t)k * S + t];
    rs[t] = a;
    float b = 0.f;
    #pragma unroll 16
    for (int k = 0; k < NBH; ++k) b += csp[(size_t)k * S + t];
    cs[t] = b;
}

extern "C" void kernel_launch(void* const* d_in, const int* in_sizes, int n_in,
                              void* d_out, int out_size, void* d_ws, size_t ws_size,
                              hipStream_t stream)
{
    const float* X    = (const float*)d_in[0];
    const float* L    = (const float*)d_in[1];
    const float* bias = (const float*)d_in[2];
    const float* coup = (const float*)d_in[3];
    float* out = (float*)d_out;

    const size_t S    = (size_t)Ndim * Odim * Hdim;    // 131072
    const size_t NL16 = (size_t)Odim * Cdim * Hdim;    // 262144 rows of 16B
    const size_t need0 = NL16 * 16 * 2 + (NBW + NBH + 2) * S * 4;  // ~80 MB
    const size_t need1 = NL16 * 16 * 2 + 2 * S * 4;                // ~9.4 MB
    dim3 grid(NBW, NBH, OSPLIT), blk(256);

    if (ws_size >= need0) {
        uint4* lsigT = (uint4*)d_ws;
        uint4* lraw  = lsigT + NL16;
        float* rsp = (float*)(lraw + NL16);
        float* csp = rsp + (size_t)NBW * S;
        float* rs  = csp + (size_t)NBH * S;
        float* cs  = rs + S;
        sylo_prep<<<dim3(1024), blk, 0, stream>>>(L, coup, lsigT, lraw);
        sylo_p0<0><<<grid, blk, 0, stream>>>(X, L, coup, lsigT, lraw, rsp, csp, rs, cs);
        sylo_reduce<<<dim3(512), blk, 0, stream>>>(rsp, csp, rs, cs);
        sylo_p1<0><<<grid, blk, 0, stream>>>(X, L, coup, bias, lsigT, lraw, out, rs, cs);
    } else if (ws_size >= need1) {
        uint4* lsigT = (uint4*)d_ws;
        uint4* lraw  = lsigT + NL16;
        float* rs = (float*)(lraw + NL16);
        float* cs = rs + S;
        hipMemsetAsync(rs, 0, 2 * S * sizeof(float), stream);
        sylo_prep<<<dim3(1024), blk, 0, stream>>>(L, coup, lsigT, lraw);
        sylo_p0<1><<<grid, blk, 0, stream>>>(X, L, coup, lsigT, lraw, nullptr, nullptr, rs, cs);
        sylo_p1<1><<<grid, blk, 0, stream>>>(X, L, coup, bias, lsigT, lraw, out, rs, cs);
    } else {
        float* rs = (float*)d_ws;
        float* cs = rs + S;
        hipMemsetAsync(rs, 0, 2 * S * sizeof(float), stream);
        sylo_p0<2><<<grid, blk, 0, stream>>>(X, L, coup, nullptr, nullptr, nullptr, nullptr, rs, cs);
        sylo_p1<2><<<grid, blk, 0, stream>>>(X, L, coup, bias, nullptr, nullptr, out, rs, cs);
    }
}

// Round 9
// 322.167 us; speedup vs baseline: 1.6503x; 1.6503x over previous
//
#include <hip/hip_runtime.h>
#include <cstdint>
#include <cstddef>
#include <utility>

#define Ndim 8
#define Odim 32
#define Cdim 16
#define Hdim 512
#define Rdim 8
#define TW 64
#define TH 4
#define NBW (Hdim/TW)     // 8   w-blocks
#define NBH (Hdim/TH)     // 128 h-blocks
#define HHsz ((size_t)Hdim*Hdim)

typedef _Float16 half2_t __attribute__((ext_vector_type(2)));
typedef unsigned int u32x4 __attribute__((ext_vector_type(4)));   // asm-friendly 128b

union U16 { u32x4 u; half2_t h[4]; };

// compile-time unroll with literal indices
template <class F, int... Is>
__device__ __forceinline__ void unroll_impl(F&& f, std::integer_sequence<int, Is...>) {
    (f(std::integral_constant<int, Is>{}), ...);
}
template <int N, class F>
__device__ __forceinline__ void unrollN(F&& f) {
    unroll_impl(static_cast<F&&>(f), std::make_integer_sequence<int, N>{});
}

__device__ __forceinline__ half2_t pk(float a, float b) {
    half2_t h; h[0] = (_Float16)a; h[1] = (_Float16)b; return h;
}

#if defined(__has_builtin)
#if __has_builtin(__builtin_amdgcn_fdot2)
#define HAVE_FDOT2 1
#endif
#endif

__device__ __forceinline__ float fdot2f(half2_t a, half2_t b, float acc) {
#ifdef HAVE_FDOT2
    return __builtin_amdgcn_fdot2(a, b, acc, false);
#else
    return acc + (float)a[0] * (float)b[0] + (float)a[1] * (float)b[1];
#endif
}

__device__ __forceinline__ void stage16(const u32x4* g, u32x4* l) {
    __builtin_amdgcn_global_load_lds(
        (const __attribute__((address_space(1))) uint32_t*)g,
        (__attribute__((address_space(3))) uint32_t*)l, 16, 0, 0);
}

template<int CTRL>
__device__ __forceinline__ float dppadd(float v) {
    return v + __int_as_float(__builtin_amdgcn_update_dpp(
        0, __float_as_int(v), CTRL, 0xf, 0xf, true));
}
__device__ __forceinline__ float wave_sum63(float v) {
    v = dppadd<0xB1>(v);
    v = dppadd<0x4E>(v);
    v = dppadd<0x141>(v);
    v = dppadd<0x140>(v);
    v = dppadd<0x142>(v);
    v = dppadd<0x143>(v);
    return v;
}

// ---- L prep: lsigT[(o*H+h)*C+c] = f16(L*coup); lraw[(o*C+c)*H+w] = f16(L) ----
__global__ __launch_bounds__(256)
void sylo_prep(const float* __restrict__ L, const float* __restrict__ coup,
               u32x4* __restrict__ lsigT, u32x4* __restrict__ lraw)
{
    int row = blockIdx.x * 256 + threadIdx.x;      // (o*C + c)*H + h
    int oc = row >> 9, h = row & 511;
    int o = oc >> 4, c = oc & 15;
    const float4* lp = (const float4*)(L + (size_t)row * Rdim);
    const float4* cp = (const float4*)(coup + (size_t)oc * Rdim);
    float4 l0 = lp[0], l1 = lp[1];
    float4 c0 = cp[0], c1 = cp[1];
    U16 s, r;
    s.h[0] = pk(l0.x * c0.x, l0.y * c0.y); s.h[1] = pk(l0.z * c0.z, l0.w * c0.w);
    s.h[2] = pk(l1.x * c1.x, l1.y * c1.y); s.h[3] = pk(l1.z * c1.z, l1.w * c1.w);
    r.h[0] = pk(l0.x, l0.y); r.h[1] = pk(l0.z, l0.w);
    r.h[2] = pk(l1.x, l1.y); r.h[3] = pk(l1.z, l1.w);
    lsigT[((size_t)o * Hdim + h) * Cdim + c] = s.u;
    lraw[row] = r.u;
}

// ---- X prep: Xh[pxblk*1024 + k*64 + pxl] = u32x4 of half2 pairs (cp*8+n) 4k..4k+3 ----
__global__ __launch_bounds__(256)
void sylo_xprep(const float* __restrict__ X, u32x4* __restrict__ Xh)
{
    int cid = blockIdx.x * 256 + threadIdx.x;     // (pxblk*16 + k)*64 + pxl
    int pxl = cid & 63;
    int k = (cid >> 6) & 15;
    size_t px = (size_t)(cid >> 10) * 64 + pxl;
    U16 v;
    unrollN<4>([&](auto ii) {
        constexpr int i = decltype(ii)::value;
        int pr = 4 * k + i;                       // pair index = cp*8 + n
        int cp = pr >> 3, n = pr & 7;
        float a = X[(size_t)(n * Cdim + 2 * cp)     * HHsz + px];
        float b = X[(size_t)(n * Cdim + 2 * cp + 1) * HHsz + px];
        v.h[i] = pk(a, b);
    });
    Xh[cid] = v.u;
}

// ---- X into registers: 16 coalesced 16B loads, then hard-pin all 64 VGPRs ----
template<int XH>
__device__ __forceinline__ void load_x(U16 (&xr)[16], const u32x4* __restrict__ Xh,
                                       const float* __restrict__ Xg,
                                       int hh, int bw, int j)
{
    if constexpr (XH) {
        const size_t base = ((size_t)hh * NBW + bw) * 1024 + j;
        unrollN<16>([&](auto ki) {
            constexpr int k = decltype(ki)::value;
            xr[k].u = Xh[base + k * 64];
        });
    } else {
        const size_t q = (size_t)hh * Hdim + bw * TW + j;
        unrollN<8>([&](auto cpi) {                 // chunked + fenced: no pressure spike
            constexpr int cp = decltype(cpi)::value;
            unrollN<8>([&](auto ni) {
                constexpr int n = decltype(ni)::value;
                constexpr int idx = cp * 8 + n;
                xr[idx >> 2].h[idx & 3] = pk(Xg[(size_t)(n * Cdim + 2 * cp) * HHsz + q],
                                             Xg[(size_t)(n * Cdim + 2 * cp + 1) * HHsz + q]);
            });
            __builtin_amdgcn_sched_barrier(0);
        });
    }
    asm volatile("" :
        "+v"(xr[0].u), "+v"(xr[1].u), "+v"(xr[2].u), "+v"(xr[3].u),
        "+v"(xr[4].u), "+v"(xr[5].u), "+v"(xr[6].u), "+v"(xr[7].u),
        "+v"(xr[8].u), "+v"(xr[9].u), "+v"(xr[10].u), "+v"(xr[11].u),
        "+v"(xr[12].u), "+v"(xr[13].u), "+v"(xr[14].u), "+v"(xr[15].u));
}

// ---- staging helpers ----
__device__ __forceinline__ void stage_tile(const u32x4* __restrict__ lraw, int o,
                                           int w0, int j, int iw, u32x4 (&buf)[Cdim][TW])
{
    unrollN<4>([&](auto ki) {
        constexpr int k = decltype(ki)::value;
        int c = iw * 4 + k;
        stage16(lraw + ((size_t)(o * Cdim + c) * Hdim + w0 + j), &buf[c][0]);
    });
}
__device__ __forceinline__ void stage_tile_raw(const float* __restrict__ Lg, int o,
                                               int w0, int tid, u32x4 (&buf)[Cdim][TW])
{
    unrollN<4>([&](auto ki) {
        constexpr int k = decltype(ki)::value;
        int e = tid + k * 256, c = e >> 6, w = e & 63;
        const float4* gp = (const float4*)(Lg + ((size_t)(o * Cdim + c) * Hdim + w0 + w) * Rdim);
        float4 l0 = gp[0], l1 = gp[1];
        U16 t;
        t.h[0] = pk(l0.x, l0.y); t.h[1] = pk(l0.z, l0.w);
        t.h[2] = pk(l1.x, l1.y); t.h[3] = pk(l1.z, l1.w);
        buf[c][w] = t.u;
    });
}

// ---- fused T+P with hoist-capping fences ----
template<int LP>
__device__ __forceinline__ void compute_p(
    int o, int ruh, int j, const u32x4 (&lwb)[Cdim][TW],
    const u32x4* __restrict__ lsigT, const float* __restrict__ Lg,
    const float* __restrict__ coupg, const U16 (&xr)[16], float (&p)[Ndim])
{
    unrollN<8>([&](auto ni) { p[decltype(ni)::value] = 0.f; });
    unrollN<8>([&](auto cpi) {
        constexpr int cp = decltype(cpi)::value;
        float tv0 = 0.f, tv1 = 0.f;
        unrollN<2>([&](auto hi) {
            constexpr int hf = decltype(hi)::value;
            constexpr int c = 2 * cp + hf;
            U16 A, B;
            if constexpr (LP) {
                A.u = lsigT[((size_t)o * Hdim + ruh) * Cdim + c];
            } else {
                const float4* a0 = (const float4*)(Lg + ((size_t)(o * Cdim + c) * Hdim + ruh) * Rdim);
                const float4* cpp = (const float4*)(coupg + (size_t)(o * Cdim + c) * Rdim);
                float4 l0 = a0[0], l1 = a0[1];
                float4 c0 = cpp[0], c1 = cpp[1];
                A.h[0] = pk(l0.x * c0.x, l0.y * c0.y); A.h[1] = pk(l0.z * c0.z, l0.w * c0.w);
                A.h[2] = pk(l1.x * c1.x, l1.y * c1.y); A.h[3] = pk(l1.z * c1.z, l1.w * c1.w);
            }
            B.u = lwb[c][j];
            float t = 0.f;
            unrollN<4>([&](auto ri) {
                constexpr int r = decltype(ri)::value;
                t = fdot2f(A.h[r], B.h[r], t);
            });
            if constexpr (hf == 0) tv0 = t; else tv1 = t;
        });
        half2_t t2 = pk(tv0, tv1);
        unrollN<8>([&](auto ni) {
            constexpr int n = decltype(ni)::value;
            constexpr int idx = cp * 8 + n;
            p[n] = fdot2f(t2, xr[idx >> 2].h[idx & 3], p[n]);
        });
        if constexpr (cp == 1 || cp == 3 || cp == 5)
            __builtin_amdgcn_sched_barrier(0);     // cap ds_read hoisting (<=4 b128 in flight)
    });
}

// ---- PASS 0: row sums (DPP) + col partials (exclusive slots) ----
template<int XH, int LP, int DET>
__global__ __launch_bounds__(256, 4)
void sylo_p0(const float* __restrict__ Xg, const float* __restrict__ Lg,
             const float* __restrict__ coupg,
             const u32x4* __restrict__ Xh, const u32x4* __restrict__ lsigT,
             const u32x4* __restrict__ lraw,
             float* __restrict__ rsp, float* __restrict__ csp,
             float* __restrict__ rs, float* __restrict__ cs)
{
    const int tid = threadIdx.x;
    const int j = tid & 63, iw = tid >> 6;
    const int bw = blockIdx.x, bh = blockIdx.y;
    const int w0 = bw * TW, h0 = bh * TH;
    const int hh = h0 + iw;
    const size_t S = (size_t)Ndim * Odim * Hdim;

    __shared__ __align__(16) u32x4 lw[2][Cdim][TW];   // 32 KB dbuf
    __shared__ float csl[TH][Ndim][TW];               // 8 KB

    U16 xr[16];
    load_x<XH>(xr, Xh, Xg, hh, bw, j);
    const int ruh = __builtin_amdgcn_readfirstlane(hh);

    if (LP) stage_tile(lraw, 0, w0, j, iw, lw[0]);
    __syncthreads();

    for (int o = 0; o < Odim; ++o) {
        const int cur = LP ? (o & 1) : 0;
        if (LP) {
            if (o + 1 < Odim) stage_tile(lraw, o + 1, w0, j, iw, lw[cur ^ 1]);
        } else {
            stage_tile_raw(Lg, o, w0, tid, lw[0]);
            __syncthreads();
        }

        float p[Ndim];
        compute_p<LP>(o, ruh, j, lw[cur], lsigT, Lg, coupg, xr, p);

        unrollN<8>([&](auto ni) {
            constexpr int n = decltype(ni)::value;
            float r = wave_sum63(p[n]);
            if (j == 63) {
                size_t i0 = (size_t)(n * Odim + o) * Hdim + hh;
                if (DET) rsp[(size_t)bw * S + i0] = r;
                else atomicAdd(&rs[i0], r);
            }
            csl[iw][n][j] = p[n];
        });
        __syncthreads();
        unrollN<2>([&](auto ki) {
            constexpr int k = decltype(ki)::value;
            int f = tid + k * 256;
            int n = f >> 6, jj = f & 63;
            float v = csl[0][n][jj] + csl[1][n][jj] + csl[2][n][jj] + csl[3][n][jj];
            size_t idx = (size_t)(n * Odim + o) * Hdim + w0 + jj;
            if (DET) csp[(size_t)bh * S + idx] = v;
            else atomicAdd(&cs[idx], v);
        });
        __syncthreads();   // drains this iter's stage DMA; gates buffer + csl reuse
    }
}

// ---- PASS 1: recompute P, combine, write out ----
template<int XH, int LP>
__global__ __launch_bounds__(256, 4)
void sylo_p1(const float* __restrict__ Xg, const float* __restrict__ Lg,
             const float* __restrict__ coupg, const float* __restrict__ biasg,
             const u32x4* __restrict__ Xh, const u32x4* __restrict__ lsigT,
             const u32x4* __restrict__ lraw,
             float* __restrict__ outg,
             const float* __restrict__ rs, const float* __restrict__ cs)
{
    const int tid = threadIdx.x;
    const int j = tid & 63, iw = tid >> 6;
    const int bw = blockIdx.x, bh = blockIdx.y;
    const int w0 = bw * TW, h0 = bh * TH;
    const int hh = h0 + iw, ww = w0 + j;

    __shared__ __align__(16) u32x4 lw[2][Cdim][TW];   // 32 KB only

    U16 xr[16];
    load_x<XH>(xr, Xh, Xg, hh, bw, j);
    const int ruh = __builtin_amdgcn_readfirstlane(hh);

    if (LP) stage_tile(lraw, 0, w0, j, iw, lw[0]);
    __syncthreads();

    for (int o = 0; o < Odim; ++o) {
        const int cur = LP ? (o & 1) : 0;
        if (LP) {
            if (o + 1 < Odim) stage_tile(lraw, o + 1, w0, j, iw, lw[cur ^ 1]);
        } else {
            stage_tile_raw(Lg, o, w0, tid, lw[0]);
            __syncthreads();
        }

        float p[Ndim];
        compute_p<LP>(o, ruh, j, lw[cur], lsigT, Lg, coupg, xr, p);

        float bb = biasg[o];
        unrollN<8>([&](auto ni) {
            constexpr int n = decltype(ni)::value;
            size_t i0 = (size_t)(n * Odim + o) * Hdim;
            float rv = rs[i0 + (size_t)ruh];     // uniform -> s_load
            float cv = cs[i0 + ww];              // coalesced, L2-hot
            float v = rv + cv - p[n] + bb;
            if (hh == ww) v = 0.f;
            outg[(i0 + hh) * Hdim + ww] = v;
        });
        __syncthreads();   // drains stage DMA; gates dbuf reuse
    }
}

__global__ __launch_bounds__(256)
void sylo_reduce(const float* __restrict__ rsp, const float* __restrict__ csp,
                 float* __restrict__ rs, float* __restrict__ cs)
{
    int t = blockIdx.x * 256 + threadIdx.x;   // < 131072
    const size_t S = (size_t)Ndim * Odim * Hdim;
    float a = 0.f;
    #pragma unroll
    for (int k = 0; k < NBW; ++k) a += rsp[(size_t)k * S + t];
    rs[t] = a;
    float b = 0.f;
    #pragma unroll 16
    for (int k = 0; k < NBH; ++k) b += csp[(size_t)k * S + t];
    cs[t] = b;
}

extern "C" void kernel_launch(void* const* d_in, const int* in_sizes, int n_in,
                              void* d_out, int out_size, void* d_ws, size_t ws_size,
                              hipStream_t stream)
{
    const float* X    = (const float*)d_in[0];
    const float* L    = (const float*)d_in[1];
    const float* bias = (const float*)d_in[2];
    const float* coup = (const float*)d_in[3];
    float* out = (float*)d_out;

    const size_t S    = (size_t)Ndim * Odim * Hdim;     // 131072
    const size_t NL16 = (size_t)Odim * Cdim * Hdim;     // 262144 u32x4 rows
    const size_t NXH  = HHsz * 16;                      // 4194304 u32x4 chunks
    const size_t need0 = NL16 * 16 * 2 + NXH * 16 + (size_t)(NBW + NBH) * S * 4 + 2 * S * 4; // ~148 MB
    const size_t need1 = NL16 * 16 * 2 + NXH * 16 + 2 * S * 4;                               // ~76.5 MB
    dim3 grid(NBW, NBH), blk(256);

    if (ws_size >= need0) {
        u32x4* lsigT = (u32x4*)d_ws;
        u32x4* lraw  = lsigT + NL16;
        u32x4* Xh    = lraw + NL16;
        float* rsp = (float*)(Xh + NXH);
        float* csp = rsp + (size_t)NBW * S;
        float* rs  = csp + (size_t)NBH * S;
        float* cs  = rs + S;
        sylo_prep<<<dim3(1024), blk, 0, stream>>>(L, coup, lsigT, lraw);
        sylo_xprep<<<dim3(16384), blk, 0, stream>>>(X, Xh);
        sylo_p0<1,1,1><<<grid, blk, 0, stream>>>(X, L, coup, Xh, lsigT, lraw, rsp, csp, rs, cs);
        sylo_reduce<<<dim3(512), blk, 0, stream>>>(rsp, csp, rs, cs);
        sylo_p1<1,1><<<grid, blk, 0, stream>>>(X, L, coup, bias, Xh, lsigT, lraw, out, rs, cs);
    } else if (ws_size >= need1) {
        u32x4* lsigT = (u32x4*)d_ws;
        u32x4* lraw  = lsigT + NL16;
        u32x4* Xh    = lraw + NL16;
        float* rs = (float*)(Xh + NXH);
        float* cs = rs + S;
        hipMemsetAsync(rs, 0, 2 * S * sizeof(float), stream);
        sylo_prep<<<dim3(1024), blk, 0, stream>>>(L, coup, lsigT, lraw);
        sylo_xprep<<<dim3(16384), blk, 0, stream>>>(X, Xh);
        sylo_p0<1,1,0><<<grid, blk, 0, stream>>>(X, L, coup, Xh, lsigT, lraw, nullptr, nullptr, rs, cs);
        sylo_p1<1,1><<<grid, blk, 0, stream>>>(X, L, coup, bias, Xh, lsigT, lraw, out, rs, cs);
    } else {
        float* rs = (float*)d_ws;
        float* cs = rs + S;
        hipMemsetAsync(rs, 0, 2 * S * sizeof(float), stream);
        sylo_p0<0,0,0><<<grid, blk, 0, stream>>>(X, L, coup, nullptr, nullptr, nullptr, nullptr, nullptr, rs, cs);
        sylo_p1<0,0><<<grid, blk, 0, stream>>>(X, L, coup, bias, nullptr, nullptr, nullptr, out, rs, cs);
    }
}